// Round 9
// baseline (608.145 us; speedup 1.0000x reference)
//
#include <hip/hip_runtime.h>

#define N_NODES   50000
#define N_EDGES   800000
#define DF        64          // feature dim (D_IN == D_HID == 64)
#define N_GRAPHS  64
#define NPAD      50176       // 98*512, padded node count

// ---- two-level counting-sort CSR build (no global atomics, no write amp) ----
#define ABLK 200              // binning blocks
#define AEDG (N_EDGES/ABLK)   // 4000 edges per block
#define RSH  9                // 512 nodes per region
#define NREG 98               // 98*512 = 50176 >= N_NODES
#define RPAD 128              // padded region count
#define CAP  12288            // LDS esrc image capacity per region (avg 8163)

// Pass A1: per-block region histogram -> H transposed [region][block]
__global__ __launch_bounds__(256)
void k_hist(const int* __restrict__ col, int* __restrict__ H) {
    __shared__ int h[RPAD];
    const int t = threadIdx.x, b = blockIdx.x;
    if (t < RPAD) h[t] = 0;
    __syncthreads();
    const int e0 = b * AEDG;
    for (int i = t; i < AEDG; i += 256)
        atomicAdd(&h[col[e0 + i] >> RSH], 1);
    __syncthreads();
    if (t < RPAD) H[t * ABLK + b] = h[t];
}

// Pass A2: one block PER REGION: exclusive scan of H[r][0..199] -> O, total -> T
__global__ __launch_bounds__(256)
void k_scanH(const int* __restrict__ H, int* __restrict__ O,
             int* __restrict__ T) {
    __shared__ int s[256];
    const int t = threadIdx.x, r = blockIdx.x;
    int v = (t < ABLK) ? H[r * ABLK + t] : 0;
    s[t] = v; __syncthreads();
    #pragma unroll
    for (int off = 1; off < 256; off <<= 1) {
        int x = (t >= off) ? s[t - off] : 0;
        __syncthreads();
        s[t] += x;
        __syncthreads();
    }
    if (t < ABLK) O[r * ABLK + t] = s[t] - v;   // exclusive, region-local
    if (t == 255) T[r] = s[255];
}

// Pass A3: scatter packed edges into region-sorted staging (block-local runs).
// Region starts R derived from T inline (128-elem LDS scan).
__global__ __launch_bounds__(256)
void k_bin(const int* __restrict__ row, const int* __restrict__ col,
           const int* __restrict__ O, const int* __restrict__ T,
           unsigned* __restrict__ staging) {
    __shared__ int cur[RPAD];
    __shared__ int rs[RPAD];
    const int t = threadIdx.x, b = blockIdx.x;
    int v = 0;
    if (t < RPAD) { v = T[t]; rs[t] = v; }
    __syncthreads();
    #pragma unroll
    for (int off = 1; off < RPAD; off <<= 1) {
        int x = 0;
        if (t < RPAD && t >= off) x = rs[t - off];
        __syncthreads();
        if (t < RPAD) rs[t] += x;
        __syncthreads();
    }
    if (t < RPAD) cur[t] = O[t * ABLK + b] + (rs[t] - v);   // + R[t]
    __syncthreads();
    const int e0 = b * AEDG;
    for (int i = t; i < AEDG; i += 256) {
        int c = col[e0 + i];
        int rr = row[e0 + i];
        int slot = atomicAdd(&cur[c >> RSH], 1);      // LDS atomic
        staging[slot] = ((unsigned)c << 16) | (unsigned)rr;
    }
}

// Pass B: one block per region -> offs, dinv, esrc (all coalesced writes)
__global__ __launch_bounds__(512)
void k_csr(const unsigned* __restrict__ staging, const int* __restrict__ T,
           int* __restrict__ offs, float* __restrict__ dinv,
           int* __restrict__ esrc) {
    __shared__ int hist[512];
    __shared__ int cur[512];
    __shared__ int img[CAP];
    __shared__ int rs[RPAD];
    __shared__ int sh_s0, sh_s1;
    const int t = threadIdx.x, r = blockIdx.x;
    int v = 0;
    if (t < RPAD) { v = T[t]; rs[t] = v; }
    __syncthreads();
    #pragma unroll
    for (int off = 1; off < RPAD; off <<= 1) {
        int x = 0;
        if (t < RPAD && t >= off) x = rs[t - off];
        __syncthreads();
        if (t < RPAD) rs[t] += x;
        __syncthreads();
    }
    if (t == r) { sh_s0 = rs[t] - v; sh_s1 = rs[t]; }
    hist[t] = 0;
    __syncthreads();
    const int s0 = sh_s0, s1 = sh_s1;
    for (int i = s0 + t; i < s1; i += 512) {
        int ln = (int)(staging[i] >> 16) - (r << RSH);
        atomicAdd(&hist[ln], 1);
    }
    __syncthreads();
    int myc = hist[t];
    #pragma unroll
    for (int off = 1; off < 512; off <<= 1) {         // inclusive scan
        int x = (t >= off) ? hist[t - off] : 0;
        __syncthreads();
        hist[t] += x;
        __syncthreads();
    }
    int excl = hist[t] - myc;
    int n = (r << RSH) + t;
    offs[n] = s0 + excl;                               // incl. sentinel nodes
    if (n < N_NODES) dinv[n] = rsqrtf((float)(myc + 1));
    cur[t] = excl;
    __syncthreads();
    for (int i = s0 + t; i < s1; i += 512) {
        unsigned p = staging[i];
        int ln = (int)(p >> 16) - (r << RSH);
        int rr = (int)(p & 0xFFFFu);
        int slot = atomicAdd(&cur[ln], 1);             // LDS atomic
        if (slot < CAP) img[slot] = rr;
        else           esrc[s0 + slot] = rr;           // overflow fallback
    }
    __syncthreads();
    int cnt = s1 - s0; if (cnt > CAP) cnt = CAP;
    for (int j = t; j < cnt; j += 512) esrc[s0 + j] = img[j];
}

// ---------------- GEMM core macro: stages in/W, computes acc[4][4] ----------------
#define GB_ROWS 64
#define LDX 68

__device__ __forceinline__ void gemm_core(
        const float* __restrict__ in, const float* __restrict__ W,
        float (*XsT)[LDX], float (*Ws)[DF],
        int row0, int t, float acc[4][4]) {
    for (int idx = t * 4; idx < DF * DF; idx += 256 * 4) {
        float4 w = *(const float4*)&W[idx];
        Ws[idx >> 6][(idx & 63) + 0] = w.x;
        Ws[idx >> 6][(idx & 63) + 1] = w.y;
        Ws[idx >> 6][(idx & 63) + 2] = w.z;
        Ws[idx >> 6][(idx & 63) + 3] = w.w;
    }
    {   // stage X transposed
        const int r  = t >> 2;
        const int k0 = (t & 3) * 16;
        const int gr = row0 + r;
        const bool valid = gr < N_NODES;
        #pragma unroll
        for (int kk = 0; kk < 16; kk += 4) {
            float4 v = valid ? *(const float4*)&in[gr * DF + k0 + kk]
                             : make_float4(0.f, 0.f, 0.f, 0.f);
            XsT[k0 + kk + 0][r] = v.x;
            XsT[k0 + kk + 1][r] = v.y;
            XsT[k0 + kk + 2][r] = v.z;
            XsT[k0 + kk + 3][r] = v.w;
        }
    }
    __syncthreads();
    const int i = (t & 15) * 4;
    const int j = (t >> 4) * 4;
    #pragma unroll
    for (int k = 0; k < DF; ++k) {
        float4 xv = *(const float4*)&XsT[k][i];
        float4 wv = *(const float4*)&Ws[k][j];
        acc[0][0] += xv.x * wv.x; acc[0][1] += xv.x * wv.y;
        acc[0][2] += xv.x * wv.z; acc[0][3] += xv.x * wv.w;
        acc[1][0] += xv.y * wv.x; acc[1][1] += xv.y * wv.y;
        acc[1][2] += xv.y * wv.z; acc[1][3] += xv.y * wv.w;
        acc[2][0] += xv.z * wv.x; acc[2][1] += xv.z * wv.y;
        acc[2][2] += xv.z * wv.z; acc[2][3] += xv.z * wv.w;
        acc[3][0] += xv.w * wv.x; acc[3][1] += xv.w * wv.y;
        acc[3][2] += xv.w * wv.z; acc[3][3] += xv.w * wv.w;
    }
}

// GEMM variant A: out = dinv ⊙ relu(in @ W + b)   (pre-scaled hidden state)
__global__ __launch_bounds__(256)
void k_gemm_s(const float* __restrict__ in, const float* __restrict__ W,
              const float* __restrict__ bias, const float* __restrict__ dinv,
              float* __restrict__ out) {
    __shared__ float XsT[DF][LDX];
    __shared__ float Ws[DF][DF];
    const int t = threadIdx.x;
    const int row0 = blockIdx.x * GB_ROWS;
    float acc[4][4] = {};
    gemm_core(in, W, XsT, Ws, row0, t, acc);
    const int i = (t & 15) * 4;
    const int j = (t >> 4) * 4;
    float4 bb = *(const float4*)&bias[j];
    #pragma unroll
    for (int u = 0; u < 4; ++u) {
        int gr = row0 + i + u;
        if (gr < N_NODES) {
            float dv = dinv[gr];
            float4 o;
            o.x = acc[u][0] + bb.x; o.x = (o.x > 0.f ? o.x : 0.f) * dv;
            o.y = acc[u][1] + bb.y; o.y = (o.y > 0.f ? o.y : 0.f) * dv;
            o.z = acc[u][2] + bb.z; o.z = (o.z > 0.f ? o.z : 0.f) * dv;
            o.w = acc[u][3] + bb.w; o.w = (o.w > 0.f ? o.w : 0.f) * dv;
            *(float4*)&out[gr * DF + j] = o;
        }
    }
}

// GEMM variant B (final layer): relu(in @ W + b) accumulated into per-graph pool
__global__ __launch_bounds__(256)
void k_gemm_pool(const float* __restrict__ in, const float* __restrict__ W,
                 const float* __restrict__ bias, const int* __restrict__ batch,
                 float* __restrict__ pool) {
    __shared__ float XsT[DF][LDX];
    __shared__ float Ws[DF][DF];
    __shared__ float gpool[N_GRAPHS][DF];   // 16 KB; span+1 rows used
    const int t = threadIdx.x;
    const int row0 = blockIdx.x * GB_ROWS;

    const int g_lo = batch[row0];
    int last = row0 + 63; if (last >= N_NODES) last = N_NODES - 1;
    const int span = batch[last] - g_lo;     // 0..63

    // zero the used part of gpool (before the gemm_core sync)
    for (int idx = t; idx < (span + 1) * DF; idx += 256)
        gpool[idx >> 6][idx & 63] = 0.f;

    float acc[4][4] = {};
    gemm_core(in, W, XsT, Ws, row0, t, acc);

    const int i = (t & 15) * 4;
    const int j = (t >> 4) * 4;
    float4 bb = *(const float4*)&bias[j];
    #pragma unroll
    for (int u = 0; u < 4; ++u) {
        int gr = row0 + i + u;
        if (gr < N_NODES) {
            int gl = batch[gr] - g_lo;
            float ox = acc[u][0] + bb.x; ox = ox > 0.f ? ox : 0.f;
            float oy = acc[u][1] + bb.y; oy = oy > 0.f ? oy : 0.f;
            float oz = acc[u][2] + bb.z; oz = oz > 0.f ? oz : 0.f;
            float ow = acc[u][3] + bb.w; ow = ow > 0.f ? ow : 0.f;
            atomicAdd(&gpool[gl][j + 0], ox);
            atomicAdd(&gpool[gl][j + 1], oy);
            atomicAdd(&gpool[gl][j + 2], oz);
            atomicAdd(&gpool[gl][j + 3], ow);
        }
    }
    __syncthreads();
    const int d = t & 63;
    for (int gl = t >> 6; gl <= span; gl += 4)
        atomicAdd(&pool[(g_lo + gl) * DF + d], gpool[gl][d]);
}

// ---------------- gather L1 (unscaled input): per-edge dinv ----------------
__global__ __launch_bounds__(256)
void k_gather(const int* __restrict__ offs, const int* __restrict__ esrc,
              const float* __restrict__ dinv, const float* __restrict__ h,
              float* __restrict__ agg) {
    const int n = blockIdx.x * 4 + (threadIdx.x >> 6);
    if (n >= N_NODES) return;
    const int l = threadIdx.x & 63;
    const int g = l >> 4;       // edge group 0..3
    const int q = l & 15;       // feature quad 0..15

    const float dc = dinv[n];
    float ax = 0.f, ay = 0.f, az = 0.f, aw = 0.f;

    if (g == 0) {               // self-loop in group 0
        float4 xv = *(const float4*)&h[n * DF + q * 4];
        ax = xv.x * dc; ay = xv.y * dc; az = xv.z * dc; aw = xv.w * dc;
    }

    const int s1 = offs[n + 1];
    int s = offs[n];
    for (; s + 16 <= s1; s += 16) {
        int r0 = esrc[s + g];
        int r1 = esrc[s + 4 + g];
        int r2 = esrc[s + 8 + g];
        int r3 = esrc[s + 12 + g];
        float w0 = dinv[r0], w1 = dinv[r1], w2 = dinv[r2], w3 = dinv[r3];
        float4 v0 = *(const float4*)&h[r0 * DF + q * 4];
        float4 v1 = *(const float4*)&h[r1 * DF + q * 4];
        float4 v2 = *(const float4*)&h[r2 * DF + q * 4];
        float4 v3 = *(const float4*)&h[r3 * DF + q * 4];
        ax += v0.x * w0; ay += v0.y * w0; az += v0.z * w0; aw += v0.w * w0;
        ax += v1.x * w1; ay += v1.y * w1; az += v1.z * w1; aw += v1.w * w1;
        ax += v2.x * w2; ay += v2.y * w2; az += v2.z * w2; aw += v2.w * w2;
        ax += v3.x * w3; ay += v3.y * w3; az += v3.z * w3; aw += v3.w * w3;
    }
    for (; s + 8 <= s1; s += 8) {
        int r0 = esrc[s + g];
        int r1 = esrc[s + 4 + g];
        float w0 = dinv[r0], w1 = dinv[r1];
        float4 v0 = *(const float4*)&h[r0 * DF + q * 4];
        float4 v1 = *(const float4*)&h[r1 * DF + q * 4];
        ax += v0.x * w0; ay += v0.y * w0; az += v0.z * w0; aw += v0.w * w0;
        ax += v1.x * w1; ay += v1.y * w1; az += v1.z * w1; aw += v1.w * w1;
    }
    for (; s < s1; s += 4) {
        int idx = s + g;
        bool valid = idx < s1;
        int r = valid ? esrc[idx] : n;
        float w = valid ? dinv[r] : 0.f;
        float4 v = *(const float4*)&h[r * DF + q * 4];
        ax += v.x * w; ay += v.y * w; az += v.z * w; aw += v.w * w;
    }

    ax += __shfl_xor(ax, 16); ay += __shfl_xor(ay, 16);
    az += __shfl_xor(az, 16); aw += __shfl_xor(aw, 16);
    ax += __shfl_xor(ax, 32); ay += __shfl_xor(ay, 32);
    az += __shfl_xor(az, 32); aw += __shfl_xor(aw, 32);

    if (l < 16)
        *(float4*)&agg[n * DF + q * 4] =
            make_float4(ax * dc, ay * dc, az * dc, aw * dc);
}

// ---------------- gather L2/L3: hs already dinv-scaled; no per-edge dinv ----------------
__global__ __launch_bounds__(256)
void k_gather_s(const int* __restrict__ offs, const int* __restrict__ esrc,
                const float* __restrict__ dinv, const float* __restrict__ hs,
                float* __restrict__ agg) {
    const int n = blockIdx.x * 4 + (threadIdx.x >> 6);
    if (n >= N_NODES) return;
    const int l = threadIdx.x & 63;
    const int g = l >> 4;
    const int q = l & 15;

    float ax = 0.f, ay = 0.f, az = 0.f, aw = 0.f;

    if (g == 0) {               // self-loop: hs[n] already has dinv[n]
        float4 xv = *(const float4*)&hs[n * DF + q * 4];
        ax = xv.x; ay = xv.y; az = xv.z; aw = xv.w;
    }

    const int s1 = offs[n + 1];
    int s = offs[n];
    for (; s + 16 <= s1; s += 16) {
        int r0 = esrc[s + g];
        int r1 = esrc[s + 4 + g];
        int r2 = esrc[s + 8 + g];
        int r3 = esrc[s + 12 + g];
        float4 v0 = *(const float4*)&hs[r0 * DF + q * 4];
        float4 v1 = *(const float4*)&hs[r1 * DF + q * 4];
        float4 v2 = *(const float4*)&hs[r2 * DF + q * 4];
        float4 v3 = *(const float4*)&hs[r3 * DF + q * 4];
        ax += v0.x + v1.x + v2.x + v3.x;
        ay += v0.y + v1.y + v2.y + v3.y;
        az += v0.z + v1.z + v2.z + v3.z;
        aw += v0.w + v1.w + v2.w + v3.w;
    }
    for (; s + 8 <= s1; s += 8) {
        int r0 = esrc[s + g];
        int r1 = esrc[s + 4 + g];
        float4 v0 = *(const float4*)&hs[r0 * DF + q * 4];
        float4 v1 = *(const float4*)&hs[r1 * DF + q * 4];
        ax += v0.x + v1.x; ay += v0.y + v1.y;
        az += v0.z + v1.z; aw += v0.w + v1.w;
    }
    for (; s < s1; s += 4) {
        int idx = s + g;
        bool valid = idx < s1;
        int r = valid ? esrc[idx] : n;
        float w = valid ? 1.f : 0.f;
        float4 v = *(const float4*)&hs[r * DF + q * 4];
        ax += v.x * w; ay += v.y * w; az += v.z * w; aw += v.w * w;
    }

    ax += __shfl_xor(ax, 16); ay += __shfl_xor(ay, 16);
    az += __shfl_xor(az, 16); aw += __shfl_xor(aw, 16);
    ax += __shfl_xor(ax, 32); ay += __shfl_xor(ay, 32);
    az += __shfl_xor(az, 32); aw += __shfl_xor(aw, 32);

    if (l < 16) {
        const float dc = dinv[n];
        *(float4*)&agg[n * DF + q * 4] =
            make_float4(ax * dc, ay * dc, az * dc, aw * dc);
    }
}

// ---------------- final divide; counts via binary search on sorted batch ----------------
__device__ __forceinline__ int lb(const int* a, int n, int key) {
    int lo = 0, hi = n;
    while (lo < hi) { int m = (lo + hi) >> 1; if (a[m] < key) lo = m + 1; else hi = m; }
    return lo;
}

__global__ void k_div(const float* __restrict__ pool, const int* __restrict__ batch,
                      float* __restrict__ out) {
    int idx = blockIdx.x * blockDim.x + threadIdx.x;
    if (idx < N_GRAPHS * DF) {
        int g = idx >> 6;
        int c = lb(batch, N_NODES, g + 1) - lb(batch, N_NODES, g);
        out[idx] = pool[idx] / fmaxf((float)c, 1.0f);
    }
}

// ---------------- launch ----------------

extern "C" void kernel_launch(void* const* d_in, const int* in_sizes, int n_in,
                              void* d_out, int out_size, void* d_ws, size_t ws_size,
                              hipStream_t stream) {
    const float* x     = (const float*)d_in[0];
    const int*   ei    = (const int*)d_in[1];      // [2, E] flat: row then col
    const int*   batch = (const int*)d_in[2];
    const float* W1    = (const float*)d_in[3];
    const float* b1    = (const float*)d_in[4];
    const float* W2    = (const float*)d_in[5];
    const float* b2    = (const float*)d_in[6];
    const float* W3    = (const float*)d_in[7];
    const float* b3    = (const float*)d_in[8];
    float* out = (float*)d_out;

    const int* row = ei;             // source
    const int* col = ei + N_EDGES;   // target (aggregation index)

    // workspace layout (4-byte elements)
    char* wsb = (char*)d_ws;
    float*    pool    = (float*)wsb;                     // N_GRAPHS*DF
    int*      H       = (int*)(pool + N_GRAPHS * DF);    // RPAD*ABLK (transposed)
    int*      O       = H + RPAD * ABLK;                 // RPAD*ABLK (transposed)
    int*      T       = O + RPAD * ABLK;                 // RPAD
    int*      offs    = T + RPAD;                        // NPAD
    int*      esrc    = offs + NPAD;                     // N_EDGES
    unsigned* staging = (unsigned*)(esrc + N_EDGES);     // N_EDGES
    float*    dinv    = (float*)(staging + N_EDGES);     // NPAD
    float*    bufA    = dinv + NPAD;                     // N_NODES*DF
    float*    bufB    = bufA + N_NODES * DF;             // N_NODES*DF

    const int nblk_G  = (N_NODES + GB_ROWS - 1) / GB_ROWS;   // 782
    const int nblk_GA = (N_NODES + 3) / 4;                   // 12500

    // zero pool only
    hipMemsetAsync(pool, 0, N_GRAPHS * DF * sizeof(float), stream);

    // CSR build: hist -> per-region scan -> bin -> per-region CSR
    k_hist<<<ABLK, 256, 0, stream>>>(col, H);
    k_scanH<<<RPAD, 256, 0, stream>>>(H, O, T);
    k_bin<<<ABLK, 256, 0, stream>>>(row, col, O, T, staging);
    k_csr<<<NREG, 512, 0, stream>>>(staging, T, offs, dinv, esrc);

    // layer 1: agg1 = A_hat x ; h1s = dinv ⊙ relu(agg1 @ W1 + b1)
    k_gather<<<nblk_GA, 256, 0, stream>>>(offs, esrc, dinv, x, bufA);
    k_gemm_s<<<nblk_G, 256, 0, stream>>>(bufA, W1, b1, dinv, bufB);
    // layer 2
    k_gather_s<<<nblk_GA, 256, 0, stream>>>(offs, esrc, dinv, bufB, bufA);
    k_gemm_s<<<nblk_G, 256, 0, stream>>>(bufA, W2, b2, dinv, bufB);
    // layer 3: gather, then gemm with fused per-graph pooling
    k_gather_s<<<nblk_GA, 256, 0, stream>>>(offs, esrc, dinv, bufB, bufA);
    k_gemm_pool<<<nblk_G, 256, 0, stream>>>(bufA, W3, b3, batch, pool);

    // mean = pool / count (counts via binary search, no atomics)
    k_div<<<(N_GRAPHS * DF + 255) / 256, 256, 0, stream>>>(pool, batch, out);
}